// Round 3
// baseline (133.941 us; speedup 1.0000x reference)
//
#include <hip/hip_runtime.h>
#include <hip/hip_bf16.h>
#include <cstdint>

// Problem constants
#define BB 4
#define LL 512
#define DD 64
#define HH 128
#define NEGV -1000000000.0f

__device__ __forceinline__ void fma4(float4& a, float s, const float4& w) {
    a.x += s * w.x; a.y += s * w.y; a.z += s * w.z; a.w += s * w.w;
}
__device__ __forceinline__ float4 f4max(const float4 a, const float4 b) {
    return make_float4(fmaxf(a.x,b.x), fmaxf(a.y,b.y), fmaxf(a.z,b.z), fmaxf(a.w,b.w));
}
__device__ __forceinline__ float4 f4add(const float4 a, const float4 b) {
    return make_float4(a.x+b.x, a.y+b.y, a.z+b.z, a.w+b.w);
}
__device__ __forceinline__ float4 f4expsub(const float4 v, const float4 m) {
    return make_float4(__expf(v.x-m.x), __expf(v.y-m.y), __expf(v.z-m.z), __expf(v.w-m.w));
}
__device__ __forceinline__ float4 f4mul(const float4 a, const float4 b) {
    return make_float4(a.x*b.x, a.y*b.y, a.z*b.z, a.w*b.w);
}
__device__ __forceinline__ float4 f4log(const float4 a) {
    return make_float4(__logf(a.x), __logf(a.y), __logf(a.z), __logf(a.w));
}

// ---------------------------------------------------------------------------
// K1: pi' = x @ W1[:64] + b1 ; pj = x @ W1[64:]
// grid 256 blocks x 256 threads; block handles 8 rows of the 2048 (b,l) rows.
// ---------------------------------------------------------------------------
__global__ __launch_bounds__(256) void k_pipj(
    const float* __restrict__ x, const float* __restrict__ W1,
    const float* __restrict__ b1, float* __restrict__ pi, float* __restrict__ pj)
{
    int t = threadIdx.x;
    int hq = t & 63;            // h-quad 0..63 (covers 256 outputs: 128 pi + 128 pj)
    int rr = t >> 6;            // 0..3
    int half = hq >> 5;         // 0: pi, 1: pj
    int hc = (hq & 31) << 2;    // h column 0..124
    int row0 = blockIdx.x * 8 + rr;       // rows row0, row0+4

    const float* Wb = W1 + half * 64 * HH + hc;   // row d: Wb + d*128
    float4 acc0;
    if (half == 0) acc0 = *(const float4*)(b1 + hc);
    else           acc0 = make_float4(0.f, 0.f, 0.f, 0.f);
    float4 acc1 = acc0;

    const float* x0 = x + (size_t)row0 * DD;
    const float* x1 = x + (size_t)(row0 + 4) * DD;
    #pragma unroll 4
    for (int dq = 0; dq < 16; ++dq) {
        float4 xa = *(const float4*)(x0 + (dq << 2));
        float4 xb = *(const float4*)(x1 + (dq << 2));
        float4 w0 = *(const float4*)(Wb + (dq*4 + 0) * HH);
        float4 w1 = *(const float4*)(Wb + (dq*4 + 1) * HH);
        float4 w2 = *(const float4*)(Wb + (dq*4 + 2) * HH);
        float4 w3 = *(const float4*)(Wb + (dq*4 + 3) * HH);
        fma4(acc0, xa.x, w0); fma4(acc0, xa.y, w1); fma4(acc0, xa.z, w2); fma4(acc0, xa.w, w3);
        fma4(acc1, xb.x, w0); fma4(acc1, xb.y, w1); fma4(acc1, xb.z, w2); fma4(acc1, xb.w, w3);
    }
    float* dst = half ? pj : pi;
    *(float4*)(dst + (size_t)row0 * HH + hc)       = acc0;
    *(float4*)(dst + (size_t)(row0 + 4) * HH + hc) = acc1;
}

// ---------------------------------------------------------------------------
// K2: scores -> la0 = mask ? NEG : (scores + b2 + gumbel) * 2
// grid (8 j-tiles, 8 i-tiles, 4 batches), 256 threads; 64x64 output tile.
// pi/pj tiles staged in LDS with XOR swizzle (key = (i>>2)&7) for
// conflict-free ds_read_b128 fragment loads.
// ---------------------------------------------------------------------------
__global__ __launch_bounds__(256) void k_scores(
    const float* __restrict__ pig, const float* __restrict__ pjg,
    const float* __restrict__ W2g, const float* __restrict__ b2g,
    const float* __restrict__ gum, const int* __restrict__ slens,
    float* __restrict__ la)
{
    __shared__ float sp[64 * HH];
    __shared__ float sq[64 * HH];
    __shared__ float sw2[HH];

    int t = threadIdx.x;
    int b = blockIdx.z;
    int i0 = blockIdx.y * 64;
    int j0 = blockIdx.x * 64;
    int rowb = b * LL + i0;
    int colb = b * LL + j0;

    // stage (swizzled)
    #pragma unroll
    for (int k = 0; k < 8; ++k) {
        int flat = (k << 8) + t;           // 0..2047 quad index
        int i = flat >> 5;                 // row 0..63
        int q = flat & 31;                 // quad 0..31
        int dq = q ^ ((i >> 2) & 7);
        float4 va = *(const float4*)(pig + ((size_t)(rowb + i)) * HH + (q << 2));
        float4 vb = *(const float4*)(pjg + ((size_t)(colb + i)) * HH + (q << 2));
        *(float4*)(sp + i * HH + (dq << 2)) = va;
        *(float4*)(sq + i * HH + (dq << 2)) = vb;
    }
    if (t < HH) sw2[t] = W2g[t];
    __syncthreads();

    int w = t >> 6, lane = t & 63;
    int ti = ((w >> 1) << 3) + (lane >> 3);   // 0..15
    int tj = ((w & 1) << 3) + (lane & 7);     // 0..15
    int kti = ti & 7, ktj = tj & 7;

    float acc[4][4];
    #pragma unroll
    for (int a = 0; a < 4; ++a)
        #pragma unroll
        for (int c = 0; c < 4; ++c) acc[a][c] = 0.f;

    for (int hq = 0; hq < 32; ++hq) {
        float4 w4 = *(const float4*)(sw2 + (hq << 2));
        int offi = (hq ^ kti) << 2;
        int offj = (hq ^ ktj) << 2;
        float4 pa[4], pb[4];
        #pragma unroll
        for (int a = 0; a < 4; ++a) pa[a] = *(const float4*)(sp + (4*ti + a) * HH + offi);
        #pragma unroll
        for (int c = 0; c < 4; ++c) pb[c] = *(const float4*)(sq + (4*tj + c) * HH + offj);
        #pragma unroll
        for (int a = 0; a < 4; ++a) {
            #pragma unroll
            for (int c = 0; c < 4; ++c) {
                float t0 = fmaxf(pa[a].x + pb[c].x, 0.f);
                float t1 = fmaxf(pa[a].y + pb[c].y, 0.f);
                float t2 = fmaxf(pa[a].z + pb[c].z, 0.f);
                float t3 = fmaxf(pa[a].w + pb[c].w, 0.f);
                float s = acc[a][c];
                s += t0 * w4.x; s += t1 * w4.y; s += t2 * w4.z; s += t3 * w4.w;
                acc[a][c] = s;
            }
        }
    }

    int sl = slens[b];
    float bb2 = b2g[0];
    int jb = j0 + 4 * tj;
    #pragma unroll
    for (int a = 0; a < 4; ++a) {
        int ig = i0 + 4 * ti + a;
        float4 g = *(const float4*)(gum + ((size_t)(b * LL + ig)) * LL + jb);
        bool iv = ig < sl;
        float4 o;
        o.x = (iv && (jb + 0) < sl) ? (acc[a][0] + bb2 + g.x) * 2.0f : NEGV;
        o.y = (iv && (jb + 1) < sl) ? (acc[a][1] + bb2 + g.y) * 2.0f : NEGV;
        o.z = (iv && (jb + 2) < sl) ? (acc[a][2] + bb2 + g.z) * 2.0f : NEGV;
        o.w = (iv && (jb + 3) < sl) ? (acc[a][3] + bb2 + g.w) * 2.0f : NEGV;
        *(float4*)(la + ((size_t)(b * LL + ig)) * LL + jb) = o;
    }
}

// ---------------------------------------------------------------------------
// K3: row normalize: la[row,:] -= (max + log(sum(exp(x-max))))
// One wave per row; 512 blocks x 256 threads. NOTE: lse = m + logf(s) order
// reproduces the fp32 absorption (-1e9 + log512 -> -1e9) for padded rows.
// ---------------------------------------------------------------------------
__global__ __launch_bounds__(256) void k_rownorm(float* __restrict__ la)
{
    int wid = (blockIdx.x << 2) + (threadIdx.x >> 6);   // row 0..2047
    int lane = threadIdx.x & 63;
    float4* row = (float4*)(la + (size_t)wid * LL);
    float4 a = row[lane];
    float4 b = row[lane + 64];
    float m = fmaxf(fmaxf(fmaxf(a.x, a.y), fmaxf(a.z, a.w)),
                    fmaxf(fmaxf(b.x, b.y), fmaxf(b.z, b.w)));
    #pragma unroll
    for (int off = 32; off; off >>= 1) m = fmaxf(m, __shfl_xor(m, off));
    float s = __expf(a.x - m) + __expf(a.y - m) + __expf(a.z - m) + __expf(a.w - m)
            + __expf(b.x - m) + __expf(b.y - m) + __expf(b.z - m) + __expf(b.w - m);
    #pragma unroll
    for (int off = 32; off; off >>= 1) s += __shfl_xor(s, off);
    float lse = m + __logf(s);
    a.x -= lse; a.y -= lse; a.z -= lse; a.w -= lse;
    b.x -= lse; b.y -= lse; b.z -= lse; b.w -= lse;
    row[lane] = a;
    row[lane + 64] = b;
}

// ---------------------------------------------------------------------------
// K4: column normalize + re-mask. 64 blocks (4 batches x 16 col-chunks of 32
// cols) x 1024 threads. Values held in registers between the LSE and the
// subtract (one global read + one write). If last: write perm=exp(.), masked
// ->0, and produce types_permed / times_permed column sums.
// ---------------------------------------------------------------------------
__global__ __launch_bounds__(1024) void k_colnorm(
    float* __restrict__ la, const int* __restrict__ slens,
    const int* __restrict__ etype, const float* __restrict__ etime,
    float* __restrict__ otype, float* __restrict__ otime, int last)
{
    __shared__ float4 Lm[1024];
    __shared__ float4 Ls[1024];
    __shared__ float4 clse[8];

    int t = threadIdx.x;
    int cg = t & 7;          // col-quad within 32-col chunk
    int rg = t >> 3;         // 0..127 row group
    int b  = blockIdx.x >> 4;
    int j0 = (blockIdx.x & 15) << 5;

    float4* base = (float4*)(la + ((size_t)b * LL) * LL + j0);  // row stride 128 float4

    float4 v[4];
    #pragma unroll
    for (int k = 0; k < 4; ++k) v[k] = base[(size_t)(4 * rg + k) * 128 + cg];

    float4 m = f4max(f4max(v[0], v[1]), f4max(v[2], v[3]));
    float4 s = f4add(f4add(f4expsub(v[0], m), f4expsub(v[1], m)),
                     f4add(f4expsub(v[2], m), f4expsub(v[3], m)));
    Lm[t] = m; Ls[t] = s;
    __syncthreads();
    for (int off = 64; off >= 1; off >>= 1) {
        if (rg < off) {
            float4 m2 = Lm[((rg + off) << 3) + cg];
            float4 s2 = Ls[((rg + off) << 3) + cg];
            float4 nm = f4max(m, m2);
            s = f4add(f4mul(s, f4expsub(m, nm)), f4mul(s2, f4expsub(m2, nm)));
            m = nm;
            Lm[t] = m; Ls[t] = s;
        }
        __syncthreads();
    }
    if (rg == 0) clse[cg] = f4add(m, f4log(s));
    __syncthreads();
    float4 lse = clse[cg];

    int sl = slens[b];
    int jb = j0 + (cg << 2);
    bool jv0 = (jb + 0) < sl, jv1 = (jb + 1) < sl, jv2 = (jb + 2) < sl, jv3 = (jb + 3) < sl;

    if (!last) {
        #pragma unroll
        for (int k = 0; k < 4; ++k) {
            int i = 4 * rg + k;
            bool iv = i < sl;
            float4 o;
            o.x = (iv && jv0) ? v[k].x - lse.x : NEGV;
            o.y = (iv && jv1) ? v[k].y - lse.y : NEGV;
            o.z = (iv && jv2) ? v[k].z - lse.z : NEGV;
            o.w = (iv && jv3) ? v[k].w - lse.w : NEGV;
            base[(size_t)i * 128 + cg] = o;
        }
    } else {
        float4 ty = make_float4(0.f, 0.f, 0.f, 0.f);
        float4 tm = make_float4(0.f, 0.f, 0.f, 0.f);
        #pragma unroll
        for (int k = 0; k < 4; ++k) {
            int i = 4 * rg + k;
            bool iv = i < sl;
            float etf = (float)etype[b * LL + i];
            float etm = etime[b * LL + i];
            float4 p;
            p.x = (iv && jv0) ? __expf(v[k].x - lse.x) : 0.f;
            p.y = (iv && jv1) ? __expf(v[k].y - lse.y) : 0.f;
            p.z = (iv && jv2) ? __expf(v[k].z - lse.z) : 0.f;
            p.w = (iv && jv3) ? __expf(v[k].w - lse.w) : 0.f;
            base[(size_t)i * 128 + cg] = p;
            fma4(ty, etf, p);
            fma4(tm, etm, p);
        }
        Lm[t] = ty; Ls[t] = tm;
        __syncthreads();
        for (int off = 64; off >= 1; off >>= 1) {
            if (rg < off) {
                ty = f4add(ty, Lm[((rg + off) << 3) + cg]);
                tm = f4add(tm, Ls[((rg + off) << 3) + cg]);
                Lm[t] = ty; Ls[t] = tm;
            }
            __syncthreads();
        }
        if (rg == 0) {
            *(float4*)(otype + b * LL + jb) = ty;
            *(float4*)(otime + b * LL + jb) = tm;
        }
    }
}

extern "C" void kernel_launch(void* const* d_in, const int* in_sizes, int n_in,
                              void* d_out, int out_size, void* d_ws, size_t ws_size,
                              hipStream_t stream)
{
    const float* etime = (const float*)d_in[0];
    const int*   etype = (const int*)d_in[1];
    const float* x     = (const float*)d_in[2];
    const int*   slens = (const int*)d_in[3];
    const float* gum   = (const float*)d_in[4];
    const float* W1    = (const float*)d_in[5];
    const float* b1    = (const float*)d_in[6];
    const float* W2    = (const float*)d_in[7];
    const float* b2    = (const float*)d_in[8];

    float* out   = (float*)d_out;
    float* otype = out;                 // (B,L)
    float* otime = out + BB * LL;       // (B,L)
    float* la    = out + 2 * BB * LL;   // (B,L,L): used as la during iterations,
                                        // holds perm at the end.
    float* pi = (float*)d_ws;                       // (B*L,128)
    float* pj = pi + (size_t)BB * LL * HH;          // (B*L,128)  (needs 2 MiB ws)

    k_pipj<<<256, 256, 0, stream>>>(x, W1, b1, pi, pj);
    k_scores<<<dim3(8, 8, BB), 256, 0, stream>>>(pi, pj, W2, b2, gum, slens, la);
    for (int it = 0; it < 10; ++it) {
        k_rownorm<<<512, 256, 0, stream>>>(la);
        k_colnorm<<<64, 1024, 0, stream>>>(la, slens, etype, etime, otype, otime,
                                           (it == 9) ? 1 : 0);
    }
}